// Round 8
// baseline (431.108 us; speedup 1.0000x reference)
//
#include <hip/hip_runtime.h>
#include <math.h>
#include <stddef.h>

#define D_MODEL 1024
#define NUM_HEADS 16
#define D_K 64
#define BATCH 4
#define SEQ 2048
#define BS (BATCH*SEQ)        /* 8192 */
#define BHN (BATCH*NUM_HEADS) /* 64  */

typedef short bf16x8 __attribute__((ext_vector_type(8)));
typedef float f32x4  __attribute__((ext_vector_type(4)));

#define MFMA16(a,b,c) __builtin_amdgcn_mfma_f32_16x16x32_bf16(a,b,c,0,0,0)

typedef __attribute__((address_space(1))) const unsigned int guint;
typedef __attribute__((address_space(3))) unsigned int luint;

extern "C" __device__ float __ocml_native_exp2_f32(float);   // v_exp_f32
#define EXP2(x) __ocml_native_exp2_f32(x)

static __device__ __forceinline__ unsigned short f2b(float f) {
  union { float f; unsigned int u; } cv; cv.f = f;
  unsigned int u = cv.u;
  u += 0x7fffu + ((u >> 16) & 1u);   // RTNE (inputs are finite)
  return (unsigned short)(u >> 16);
}
static __device__ __forceinline__ float b2f(unsigned short h) {
  union { unsigned int u; float f; } cv; cv.u = ((unsigned int)h) << 16;
  return cv.f;
}
// pack two floats as truncated bf16 pair in ONE v_perm: [bf16(lo) | bf16(hi)<<16]
static __device__ __forceinline__ unsigned pack_bf16x2_rtz(float lo, float hi) {
  return __builtin_amdgcn_perm(__builtin_bit_cast(unsigned, lo),
                               __builtin_bit_cast(unsigned, hi),
                               0x03020706u);
}

// ---------------- fp32 -> bf16 cast, ALL tensors in one launch ----------------
__global__ void cast_all_kernel(const float* __restrict__ x,
                                const float* __restrict__ w0, const float* __restrict__ w1,
                                const float* __restrict__ w2, const float* __restrict__ w3,
                                unsigned short* __restrict__ xb,
                                unsigned short* __restrict__ d0, unsigned short* __restrict__ d1,
                                unsigned short* __restrict__ d2, unsigned short* __restrict__ d3) {
  int i = blockIdx.x * 256 + threadIdx.x;   // 0 .. 3,145,727
  const float* s; unsigned short* d; int k;
  if (i < 2097152) {
    s = x; d = xb; k = i;
  } else {
    int r = i - 2097152;
    int w = r >> 18;            // 0..3 (262144 = 2^18 float4 per weight)
    k = r & 262143;
    switch (w) {
      case 0:  s = w0; d = d0; break;
      case 1:  s = w1; d = d1; break;
      case 2:  s = w2; d = d2; break;
      default: s = w3; d = d3; break;
    }
  }
  float4 v = ((const float4*)s)[k];
  ushort4 o;
  o.x = f2b(v.x); o.y = f2b(v.y); o.z = f2b(v.z); o.w = f2b(v.w);
  ((ushort4*)d)[k] = o;
}

// ---------------- bf16 GEMM: C[M,N] = A[M,K] * Bw[N,K]^T ----------------
// EPI==1: fused RoPE on q/k via NATIVE v_sin/v_cos (revolutions domain, fract
// reduction) — no sincosf (round-6: OCML sincos scratch -> 1.58 GB writes).
template<int EPI, int TN>
__global__ __launch_bounds__(256, 3) void gemm_bt(
    const unsigned short* __restrict__ A,
    const unsigned short* __restrict__ Bw,
    float* __restrict__ Cf,
    unsigned short* __restrict__ qb,
    unsigned short* __restrict__ kb,
    unsigned short* __restrict__ vtb,
    const int* __restrict__ pos,
    int M, int N, int K)
{
  constexpr int NJ = TN / 32;            // B-frag cols per wave (4 or 2)
  __shared__ __align__(16) unsigned short sA[128*64];
  __shared__ __align__(16) unsigned short sB[TN*64];
  const int tid  = threadIdx.x;
  const int wave = tid >> 6, lane = tid & 63;
  const int lrow = lane & 15, quad = lane >> 4;
  const int wm = (wave & 1) * 64, wn = (wave >> 1) * (TN/2);
  const int m0 = blockIdx.x * 128, n0 = blockIdx.y * TN;
  const int swz = lrow & 7;

  const f32x4 zero4 = {0.f, 0.f, 0.f, 0.f};
  f32x4 acc[4][NJ];
  for (int i = 0; i < 4; ++i)
    for (int j = 0; j < NJ; ++j) acc[i][j] = zero4;

  for (int kt = 0; kt < K; kt += 64) {
    __syncthreads();
    #pragma unroll
    for (int it = 0; it < 4; ++it) {
      int t = it*256 + tid;                 // A slot 0..1023 (16B chunks)
      int row = t >> 3;
      int c8  = (t & 7) ^ (row & 7);        // XOR-swizzled source chunk
      __builtin_amdgcn_global_load_lds(
          (guint*)&A[(size_t)(m0 + row)*K + kt + c8*8], (luint*)&sA[t*8], 16, 0, 0);
    }
    #pragma unroll
    for (int it = 0; it < TN/32; ++it) {
      int t = it*256 + tid;                 // B slot 0..TN*8-1
      int row = t >> 3;
      int c8  = (t & 7) ^ (row & 7);
      __builtin_amdgcn_global_load_lds(
          (guint*)&Bw[(size_t)(n0 + row)*K + kt + c8*8], (luint*)&sB[t*8], 16, 0, 0);
    }
    __syncthreads();
    #pragma unroll
    for (int kh = 0; kh < 2; ++kh) {
      bf16x8 af[4], bfr[NJ];
      #pragma unroll
      for (int i = 0; i < 4; ++i) {
        int ra = wm + i*16 + lrow;
        af[i] = *(const bf16x8*)&sA[ra*64 + (((kh*4 + quad) ^ swz))*8];
      }
      #pragma unroll
      for (int j = 0; j < NJ; ++j) {
        int rb = wn + j*16 + lrow;
        bfr[j] = *(const bf16x8*)&sB[rb*64 + (((kh*4 + quad) ^ swz))*8];
      }
      #pragma unroll
      for (int i = 0; i < 4; ++i)
        #pragma unroll
        for (int j = 0; j < NJ; ++j)
          acc[i][j] = MFMA16(af[i], bfr[j], acc[i][j]);
    }
  }

  if (EPI == 0) {
    for (int i = 0; i < 4; ++i)
      for (int j = 0; j < NJ; ++j)
        for (int r = 0; r < 4; ++r) {
          int m = m0 + wm + i*16 + quad*4 + r;
          int n = n0 + wn + j*16 + lrow;
          Cf[(size_t)m*N + n] = acc[i][j][r];
        }
  } else if (n0 >= 2048) {
    // V blocks: 4 r-values are s-consecutive in vt -> one packed store each
    for (int i = 0; i < 4; ++i) {
      int mb = m0 + wm + i*16 + quad*4;
      int bb = mb >> 11, s = mb & 2047;
      for (int j = 0; j < NJ; ++j) {
        int rr = (n0 + wn + j*16 + lrow) & 1023;
        size_t base = ((size_t)(bb*16 + (rr >> 6))*64 + (rr & 63))*2048 + s;
        ushort4 o;
        o.x = f2b(acc[i][j][0]); o.y = f2b(acc[i][j][1]);
        o.z = f2b(acc[i][j][2]); o.w = f2b(acc[i][j][3]);
        *(ushort4*)&vtb[base] = o;
      }
    }
  } else {
    // q/k blocks with fused RoPE (native trig, scratch-free).
    const float QS = 0.18033688011112042f;     // (1/8) * log2(e)
    const float INV2PI = 0.15915493667125702f; // 1/(2*pi)
    const bool evenl = ((lane & 1) == 0);
    const int bb = m0 >> 11;                   // batch (block-uniform)
    float rf[NJ];                              // per-lane rope factor, rev units
    #pragma unroll
    for (int j = 0; j < NJ; ++j) {
      const int jp = ((n0 + wn + j*16 + lrow) & 63) >> 1;   // pair idx 0..31
      rf[j] = exp2f(-0.4152410118609203f * (float)jp) * INV2PI;
    }
    for (int i = 0; i < 4; ++i) {
      const int mbase = m0 + wm + i*16 + quad*4;
      float ps[4];
      #pragma unroll
      for (int r = 0; r < 4; ++r) ps[r] = (float)pos[(mbase + r) & 2047];
      for (int j = 0; j < NJ; ++j) {
        const int n = n0 + wn + j*16 + lrow;
        const int which = n >> 10;             // 0 = q, 1 = k (block-uniform)
        const int rr = n & 1023, h = rr >> 6, d = rr & 63;
        const size_t bh = (size_t)(bb*16 + h);
        #pragma unroll
        for (int r = 0; r < 4; ++r) {
          const int s = (mbase + r) & 2047;
          float v = acc[i][j][r];
          float p = __shfl_xor(v, 1);          // partner (same row, d^1)
          float rev = ps[r] * rf[j];
          rev = rev - floorf(rev);             // [0,1) revolutions
          float sn = __builtin_amdgcn_sinf(rev);   // sin(2*pi*rev)
          float c  = __builtin_amdgcn_cosf(rev);
          // d even: v*c - p*sn ; d odd: v*c + p*sn
          float out = fmaf(evenl ? -p : p, sn, v * c);
          if (which == 0) out *= QS;
          unsigned short bv = f2b(out);
          if (which == 0) qb[(bh*2048 + s)*64 + d] = bv;
          else            kb[(bh*2048 + s)*64 + d] = bv;
        }
      }
    }
  }
}

// ---- causal flash attention (S^T/O^T form).
// Round-8 change: V is NO LONGER LDS-staged — read directly from global
// (L2-resident: one bh per XCD, K+V per bh = 512 KB, 8 bh x 512 KB = 4 MB
// = per-XCD L2). The PV A-operand fragment is a natural 16B/lane gather:
// Vt[rv][kv0 + half*32 + quad*8 .. +7]. Removes half the staging issues +
// their share of the barrier vmcnt drain; LDS 40960 -> 24576 B -> 6
// blocks/CU co-resident (was 4) for better latency overlap.
// K staging, sP path, supertile J-map: verified round-1 structure, unchanged.
__global__ __launch_bounds__(256, 6) void flash_kernel(
    const unsigned short* __restrict__ q,    // [bh][s][d]  (pre-scaled by log2e/8)
    const unsigned short* __restrict__ kk,   // [bh][s][d]
    const unsigned short* __restrict__ vt,   // [bh][d][s]
    unsigned short* __restrict__ attn)       // [b][s][h*64+d]
{
  __shared__ __align__(16) unsigned short sK[2][64*64];   // XOR-swizzled chunks
  __shared__ __align__(16) unsigned short sP[4][32*32];   // per-wave P^T halves
  const int tid  = threadIdx.x;
  const int wave = tid >> 6, lane = tid & 63;
  const int lrow = lane & 15, quad = lane >> 4;
  const int bh = blockIdx.x;                // XCD = bid%8 = bh%8
  const int b = bh >> 4, h = bh & 15;
  const int y = blockIdx.y;                 // 0..15
  const int J = (y < 4) ? (15 - y) : (y < 8) ? (y + 4) : (y < 12) ? (15 - y) : (y - 12);

  const unsigned short* Q  = q  + (size_t)bh * SEQ * D_K;
  const unsigned short* Kp = kk + (size_t)bh * SEQ * D_K;
  const unsigned short* Vt = vt + (size_t)bh * SEQ * D_K;
  unsigned short* sp = sP[wave];

  bf16x8 ones;
  #pragma unroll
  for (int z = 0; z < 8; ++z) ones[z] = (short)0x3F80;   // bf16 1.0
  const f32x4 zero4 = {0.f, 0.f, 0.f, 0.f};
  const int swz = lrow & 7;          // K chunk swizzle key
  const int sw2 = (lrow >> 1) & 3;   // sP 16B-granule swizzle key

  auto stage = [&](int t, int buf) {
    const int kv0 = t * 64;
    #pragma unroll
    for (int rr = 0; rr < 2; ++rr) {
      int s = rr*256 + tid;               // LDS slot 0..511 (16B chunks)
      int row = s >> 3;
      int c8  = (s & 7) ^ (row & 7);      // XOR-swizzled source chunk
      __builtin_amdgcn_global_load_lds(
          (guint*)&Kp[(size_t)(kv0 + row)*64 + c8*8], (luint*)&sK[buf][s*8], 16, 0, 0);
    }
  };

  const int T = 2*(J + 1);                // kv tiles needed by the block
  const int nt = 2*J + (wave >> 1) + 1;   // tiles needed by THIS wave
  const int q0 = J*128 + wave*32;         // this wave's first q row

  bf16x8 aq[2][2];                        // Q as B-operand [n=q][k=d]
  #pragma unroll
  for (int rh = 0; rh < 2; ++rh)
    #pragma unroll
    for (int dh = 0; dh < 2; ++dh)
      aq[rh][dh] = *(const bf16x8*)&Q[(size_t)(q0 + rh*16 + lrow)*64 + dh*32 + quad*8];

  f32x4 acc[2][4];   // O^T: acc[rh][db]: d = db*16+quad*4+r, q = lrow
  #pragma unroll
  for (int rh = 0; rh < 2; ++rh)
    #pragma unroll
    for (int db = 0; db < 4; ++db) acc[rh][db] = zero4;
  f32x4 accl[2] = {zero4, zero4};         // l[q=lrow] (all rows equal)

  stage(0, 0);             // prologue prefetch

  for (int t = 0; t < T; ++t) {
    const int kv0 = t * 64;
    const int buf = t & 1;
    __syncthreads();       // vmcnt drain -> tile t resident; buf[t+1] readers done
    if (t + 1 < T) stage(t + 1, buf ^ 1);

    if (t < nt) {
      const bool diag = (t == nt - 1);

      auto phalf = [&](int half) {
        #pragma unroll
        for (int ch = 0; ch < 2; ++ch) {
          const int c = half*2 + ch;
          const int r0 = c*16 + lrow;
          bf16x8 k0 = *(const bf16x8*)&sK[buf][(r0*8 + (quad       ^ swz))*8];
          bf16x8 k1 = *(const bf16x8*)&sK[buf][(r0*8 + ((quad + 4) ^ swz))*8];
          #pragma unroll
          for (int rh = 0; rh < 2; ++rh) {
            f32x4 st = MFMA16(k0, aq[rh][0], zero4);   // S^T subtile
            st = MFMA16(k1, aq[rh][1], st);
            if (diag) {   // causal: kv = kv0+c*16+quad*4+r, q = q0+rh*16+lrow
              #pragma unroll
              for (int r = 0; r < 4; ++r)
                if (kv0 + c*16 + quad*4 + r > q0 + rh*16 + lrow)
                  st[r] = -1e30f;
            }
            uint2 w;
            w.x = pack_bf16x2_rtz(EXP2(st[0] - 16.0f), EXP2(st[1] - 16.0f));
            w.y = pack_bf16x2_rtz(EXP2(st[2] - 16.0f), EXP2(st[3] - 16.0f));
            // write granule g16 = 2*ch + (quad>>1), XOR-swizzled by sw2
            *(uint2*)&sp[(rh*16 + lrow)*32 + (((2*ch + (quad >> 1)) ^ sw2) << 3)
                         + ((quad & 1) << 2)] = w;
          }
        }
        __builtin_amdgcn_wave_barrier();   // DS pipe in-order per wave
        bf16x8 pa0 = *(const bf16x8*)&sp[(lrow)     *32 + ((quad ^ sw2) << 3)];
        bf16x8 pa1 = *(const bf16x8*)&sp[(16 + lrow)*32 + ((quad ^ sw2) << 3)];
        #pragma unroll
        for (int db = 0; db < 4; ++db) {
          const int rv = db*16 + lrow;
          // V direct from global (L2-hit): 16B/lane gather, k = quad*8+j
          bf16x8 v = *(const bf16x8*)&Vt[(size_t)rv*2048 + kv0 + half*32 + quad*8];
          acc[0][db] = MFMA16(v, pa0, acc[0][db]);     // O^T
          acc[1][db] = MFMA16(v, pa1, acc[1][db]);
        }
        accl[0] = MFMA16(ones, pa0, accl[0]);
        accl[1] = MFMA16(ones, pa1, accl[1]);
        __builtin_amdgcn_wave_barrier();   // next half/tile writes after these reads
      };

      phalf(0);
      // diag tiles for waves 0/2 (q0 == kv0): kv half 1 entirely above the
      // causal boundary -> skip (P would be all zeros).
      if (!(diag && !(wave & 1))) phalf(1);
    }
  }

  // epilogue: O^T -> attn, 4 d-consecutive values per packed store
  #pragma unroll
  for (int rh = 0; rh < 2; ++rh) {
    float inv = 1.0f / accl[rh][0];
    size_t rowbase = ((size_t)(b*SEQ + q0 + rh*16 + lrow))*D_MODEL + h*64;
    #pragma unroll
    for (int db = 0; db < 4; ++db) {
      ushort4 o;
      o.x = f2b(acc[rh][db][0] * inv);
      o.y = f2b(acc[rh][db][1] * inv);
      o.z = f2b(acc[rh][db][2] * inv);
      o.w = f2b(acc[rh][db][3] * inv);
      *(ushort4*)&attn[rowbase + db*16 + quad*4] = o;
    }
  }
}

extern "C" void kernel_launch(void* const* d_in, const int* in_sizes, int n_in,
                              void* d_out, int out_size, void* d_ws, size_t ws_size,
                              hipStream_t stream) {
  const float* x  = (const float*)d_in[0];
  const int*  pos = (const int*)d_in[1];
  const float* Wq = (const float*)d_in[2];
  const float* Wk = (const float*)d_in[3];
  const float* Wv = (const float*)d_in[4];
  const float* Wo = (const float*)d_in[5];
  float* out = (float*)d_out;

  char* ws = (char*)d_ws;
  // workspace layout (bytes); total 75,497,472
  unsigned short* xb   = (unsigned short*)(ws);              // 16 MB, reused as attn buffer
  unsigned short* wqkv = (unsigned short*)(ws + 16777216);   // 6 MB  [3072][1024]
  unsigned short* wo   = (unsigned short*)(ws + 23068672);   // 2 MB  [1024][1024]
  unsigned short* qb   = (unsigned short*)(ws + 25165824);   // 16 MB [bh][s][d]
  unsigned short* kb   = (unsigned short*)(ws + 41943040);   // 16 MB [bh][s][d]
  unsigned short* vtb  = (unsigned short*)(ws + 58720256);   // 16 MB [bh][d][s]
  unsigned short* attn = xb;                                 // reuse

  // 1) all casts in ONE launch (x + 4 weights)
  cast_all_kernel<<<12288, 256, 0, stream>>>(
      x, Wq, Wk, Wv, Wo, xb, wqkv, wqkv + 1048576, wqkv + 2097152, wo);

  // 2) QKV projection (+fused RoPE on q,k): [8192,3072] = xb * wqkv^T
  gemm_bt<1,128><<<dim3(BS/128, 3072/128), 256, 0, stream>>>(
      xb, wqkv, nullptr, qb, kb, vtb, pos, BS, 3*D_MODEL, D_MODEL);

  // 3) causal flash attention -> attn [b,s,1024] bf16
  flash_kernel<<<dim3(BHN, 16), 256, 0, stream>>>(qb, kb, vtb, attn);

  // 4) output projection: out = attn * wo^T (fp32 out), 128x128 tiles
  gemm_bt<0,128><<<dim3(BS/128, D_MODEL/128), 256, 0, stream>>>(
      attn, wo, out, nullptr, nullptr, nullptr, nullptr, BS, D_MODEL, D_MODEL);

  (void)in_sizes; (void)n_in; (void)out_size; (void)ws_size;
}

// Round 10
// 236.200 us; speedup vs baseline: 1.8252x; 1.8252x over previous
//
#include <hip/hip_runtime.h>
#include <math.h>
#include <stddef.h>

#define D_MODEL 1024
#define NUM_HEADS 16
#define D_K 64
#define BATCH 4
#define SEQ 2048
#define BS (BATCH*SEQ)        /* 8192 */
#define BHN (BATCH*NUM_HEADS) /* 64  */

typedef short bf16x8 __attribute__((ext_vector_type(8)));
typedef float f32x4  __attribute__((ext_vector_type(4)));

#define MFMA16(a,b,c) __builtin_amdgcn_mfma_f32_16x16x32_bf16(a,b,c,0,0,0)

typedef __attribute__((address_space(1))) const unsigned int guint;
typedef __attribute__((address_space(3))) unsigned int luint;

extern "C" __device__ float __ocml_native_exp2_f32(float);   // v_exp_f32
#define EXP2(x) __ocml_native_exp2_f32(x)

// Hardened same-wave LDS write->read handoff: compiler memory fence +
// HW drain of this wave's DS queue + scheduler pin. Strictly stronger than
// wave_barrier (which has NO memory semantics in LLVM and relies on the
// DS-pipe-in-order property plus scheduling luck). Round-9 post-timing
// divergence (intermittent, timing-dependent) implicates exactly this class
// of ordering fragility.
#define DS_HANDOFF_FENCE() do {                                  \
    asm volatile("s_waitcnt lgkmcnt(0)" ::: "memory");           \
    __builtin_amdgcn_sched_barrier(0);                           \
  } while (0)

static __device__ __forceinline__ unsigned short f2b(float f) {
  union { float f; unsigned int u; } cv; cv.f = f;
  unsigned int u = cv.u;
  u += 0x7fffu + ((u >> 16) & 1u);   // RTNE (inputs are finite)
  return (unsigned short)(u >> 16);
}
static __device__ __forceinline__ float b2f(unsigned short h) {
  union { unsigned int u; float f; } cv; cv.u = ((unsigned int)h) << 16;
  return cv.f;
}
// pack two floats as truncated bf16 pair in ONE v_perm: [bf16(lo) | bf16(hi)<<16]
static __device__ __forceinline__ unsigned pack_bf16x2_rtz(float lo, float hi) {
  return __builtin_amdgcn_perm(__builtin_bit_cast(unsigned, lo),
                               __builtin_bit_cast(unsigned, hi),
                               0x03020706u);
}

// ---------------- fp32 -> bf16 cast, ALL tensors in one launch ----------------
__global__ void cast_all_kernel(const float* __restrict__ x,
                                const float* __restrict__ w0, const float* __restrict__ w1,
                                const float* __restrict__ w2, const float* __restrict__ w3,
                                unsigned short* __restrict__ xb,
                                unsigned short* __restrict__ d0, unsigned short* __restrict__ d1,
                                unsigned short* __restrict__ d2, unsigned short* __restrict__ d3) {
  int i = blockIdx.x * 256 + threadIdx.x;   // 0 .. 3,145,727
  const float* s; unsigned short* d; int k;
  if (i < 2097152) {
    s = x; d = xb; k = i;
  } else {
    int r = i - 2097152;
    int w = r >> 18;            // 0..3 (262144 = 2^18 float4 per weight)
    k = r & 262143;
    switch (w) {
      case 0:  s = w0; d = d0; break;
      case 1:  s = w1; d = d1; break;
      case 2:  s = w2; d = d2; break;
      default: s = w3; d = d3; break;
    }
  }
  float4 v = ((const float4*)s)[k];
  ushort4 o;
  o.x = f2b(v.x); o.y = f2b(v.y); o.z = f2b(v.z); o.w = f2b(v.w);
  ((ushort4*)d)[k] = o;
}

// ---------------- bf16 GEMM: C[M,N] = A[M,K] * Bw[N,K]^T ----------------
// EPI==1: fused RoPE on q/k via NATIVE v_sin/v_cos (revolutions domain, fract
// reduction) — no sincosf (round-6: OCML sincos scratch -> 1.58 GB writes).
template<int EPI, int TN>
__global__ __launch_bounds__(256, 3) void gemm_bt(
    const unsigned short* __restrict__ A,
    const unsigned short* __restrict__ Bw,
    float* __restrict__ Cf,
    unsigned short* __restrict__ qb,
    unsigned short* __restrict__ kb,
    unsigned short* __restrict__ vtb,
    const int* __restrict__ pos,
    int M, int N, int K)
{
  constexpr int NJ = TN / 32;            // B-frag cols per wave (4 or 2)
  __shared__ __align__(16) unsigned short sA[128*64];
  __shared__ __align__(16) unsigned short sB[TN*64];
  const int tid  = threadIdx.x;
  const int wave = tid >> 6, lane = tid & 63;
  const int lrow = lane & 15, quad = lane >> 4;
  const int wm = (wave & 1) * 64, wn = (wave >> 1) * (TN/2);
  const int m0 = blockIdx.x * 128, n0 = blockIdx.y * TN;
  const int swz = lrow & 7;

  const f32x4 zero4 = {0.f, 0.f, 0.f, 0.f};
  f32x4 acc[4][NJ];
  for (int i = 0; i < 4; ++i)
    for (int j = 0; j < NJ; ++j) acc[i][j] = zero4;

  for (int kt = 0; kt < K; kt += 64) {
    __syncthreads();
    #pragma unroll
    for (int it = 0; it < 4; ++it) {
      int t = it*256 + tid;                 // A slot 0..1023 (16B chunks)
      int row = t >> 3;
      int c8  = (t & 7) ^ (row & 7);        // XOR-swizzled source chunk
      __builtin_amdgcn_global_load_lds(
          (guint*)&A[(size_t)(m0 + row)*K + kt + c8*8], (luint*)&sA[t*8], 16, 0, 0);
    }
    #pragma unroll
    for (int it = 0; it < TN/32; ++it) {
      int t = it*256 + tid;                 // B slot 0..TN*8-1
      int row = t >> 3;
      int c8  = (t & 7) ^ (row & 7);
      __builtin_amdgcn_global_load_lds(
          (guint*)&Bw[(size_t)(n0 + row)*K + kt + c8*8], (luint*)&sB[t*8], 16, 0, 0);
    }
    __syncthreads();
    #pragma unroll
    for (int kh = 0; kh < 2; ++kh) {
      bf16x8 af[4], bfr[NJ];
      #pragma unroll
      for (int i = 0; i < 4; ++i) {
        int ra = wm + i*16 + lrow;
        af[i] = *(const bf16x8*)&sA[ra*64 + (((kh*4 + quad) ^ swz))*8];
      }
      #pragma unroll
      for (int j = 0; j < NJ; ++j) {
        int rb = wn + j*16 + lrow;
        bfr[j] = *(const bf16x8*)&sB[rb*64 + (((kh*4 + quad) ^ swz))*8];
      }
      #pragma unroll
      for (int i = 0; i < 4; ++i)
        #pragma unroll
        for (int j = 0; j < NJ; ++j)
          acc[i][j] = MFMA16(af[i], bfr[j], acc[i][j]);
    }
  }

  if (EPI == 0) {
    for (int i = 0; i < 4; ++i)
      for (int j = 0; j < NJ; ++j)
        for (int r = 0; r < 4; ++r) {
          int m = m0 + wm + i*16 + quad*4 + r;
          int n = n0 + wn + j*16 + lrow;
          Cf[(size_t)m*N + n] = acc[i][j][r];
        }
  } else if (n0 >= 2048) {
    // V blocks: 4 r-values are s-consecutive in vt -> one packed store each
    for (int i = 0; i < 4; ++i) {
      int mb = m0 + wm + i*16 + quad*4;
      int bb = mb >> 11, s = mb & 2047;
      for (int j = 0; j < NJ; ++j) {
        int rr = (n0 + wn + j*16 + lrow) & 1023;
        size_t base = ((size_t)(bb*16 + (rr >> 6))*64 + (rr & 63))*2048 + s;
        ushort4 o;
        o.x = f2b(acc[i][j][0]); o.y = f2b(acc[i][j][1]);
        o.z = f2b(acc[i][j][2]); o.w = f2b(acc[i][j][3]);
        *(ushort4*)&vtb[base] = o;
      }
    }
  } else {
    // q/k blocks with fused RoPE (native trig, scratch-free).
    const float QS = 0.18033688011112042f;     // (1/8) * log2(e)
    const float INV2PI = 0.15915493667125702f; // 1/(2*pi)
    const bool evenl = ((lane & 1) == 0);
    const int bb = m0 >> 11;                   // batch (block-uniform)
    float rf[NJ];                              // per-lane rope factor, rev units
    #pragma unroll
    for (int j = 0; j < NJ; ++j) {
      const int jp = ((n0 + wn + j*16 + lrow) & 63) >> 1;   // pair idx 0..31
      rf[j] = exp2f(-0.4152410118609203f * (float)jp) * INV2PI;
    }
    for (int i = 0; i < 4; ++i) {
      const int mbase = m0 + wm + i*16 + quad*4;
      float ps[4];
      #pragma unroll
      for (int r = 0; r < 4; ++r) ps[r] = (float)pos[(mbase + r) & 2047];
      for (int j = 0; j < NJ; ++j) {
        const int n = n0 + wn + j*16 + lrow;
        const int which = n >> 10;             // 0 = q, 1 = k (block-uniform)
        const int rr = n & 1023, h = rr >> 6, d = rr & 63;
        const size_t bh = (size_t)(bb*16 + h);
        #pragma unroll
        for (int r = 0; r < 4; ++r) {
          const int s = (mbase + r) & 2047;
          float v = acc[i][j][r];
          float p = __shfl_xor(v, 1);          // partner (same row, d^1)
          float rev = ps[r] * rf[j];
          rev = rev - floorf(rev);             // [0,1) revolutions
          float sn = __builtin_amdgcn_sinf(rev);   // sin(2*pi*rev)
          float c  = __builtin_amdgcn_cosf(rev);
          // d even: v*c - p*sn ; d odd: v*c + p*sn
          float out = fmaf(evenl ? -p : p, sn, v * c);
          if (which == 0) out *= QS;
          unsigned short bv = f2b(out);
          if (which == 0) qb[(bh*2048 + s)*64 + d] = bv;
          else            kb[(bh*2048 + s)*64 + d] = bv;
        }
      }
    }
  }
}

// ---- causal flash attention (S^T/O^T form), double-buffered K/V staging.
// [Round-1/7 verified structure; sP same-wave handoff HARDENED this round:
//  ds_write -> s_waitcnt lgkmcnt(0)+sched_barrier -> ds_read (was
//  wave_barrier, which has no memory semantics — prime suspect for the
//  round-9 intermittent post-timing divergence).]
__global__ __launch_bounds__(256, 4) void flash_kernel(
    const unsigned short* __restrict__ q,    // [bh][s][d]  (pre-scaled by log2e/8)
    const unsigned short* __restrict__ kk,   // [bh][s][d]
    const unsigned short* __restrict__ vt,   // [bh][d][s]
    unsigned short* __restrict__ attn)       // [b][s][h*64+d]
{
  __shared__ __align__(16) unsigned short sK[2][64*64];   // XOR-swizzled chunks
  __shared__ __align__(16) unsigned short sV[2][64*64];
  __shared__ __align__(16) unsigned short sP[4][32*32];   // per-wave P^T halves
  const int tid  = threadIdx.x;
  const int wave = tid >> 6, lane = tid & 63;
  const int lrow = lane & 15, quad = lane >> 4;
  const int bh = blockIdx.x;                // XCD = bid%8 = bh%8
  const int b = bh >> 4, h = bh & 15;
  const int y = blockIdx.y;                 // 0..15
  const int J = (y < 4) ? (15 - y) : (y < 8) ? (y + 4) : (y < 12) ? (15 - y) : (y - 12);

  const unsigned short* Q  = q  + (size_t)bh * SEQ * D_K;
  const unsigned short* Kp = kk + (size_t)bh * SEQ * D_K;
  const unsigned short* Vt = vt + (size_t)bh * SEQ * D_K;
  unsigned short* sp = sP[wave];

  bf16x8 ones;
  #pragma unroll
  for (int z = 0; z < 8; ++z) ones[z] = (short)0x3F80;   // bf16 1.0
  const f32x4 zero4 = {0.f, 0.f, 0.f, 0.f};
  const int swz = lrow & 7;          // K/V chunk swizzle key
  const int sw2 = (lrow >> 1) & 3;   // sP 16B-granule swizzle key

  auto stage = [&](int t, int buf) {
    const int kv0 = t * 64;
    #pragma unroll
    for (int rr = 0; rr < 2; ++rr) {
      int s = rr*256 + tid;               // LDS slot 0..511 (16B chunks)
      int row = s >> 3;
      int c8  = (s & 7) ^ (row & 7);      // XOR-swizzled source chunk
      __builtin_amdgcn_global_load_lds(
          (guint*)&Kp[(size_t)(kv0 + row)*64 + c8*8], (luint*)&sK[buf][s*8], 16, 0, 0);
      __builtin_amdgcn_global_load_lds(
          (guint*)&Vt[(size_t)row*2048 + kv0 + c8*8], (luint*)&sV[buf][s*8], 16, 0, 0);
    }
  };

  const int T = 2*(J + 1);                // kv tiles needed by the block
  const int nt = 2*J + (wave >> 1) + 1;   // tiles needed by THIS wave
  const int q0 = J*128 + wave*32;         // this wave's first q row

  bf16x8 aq[2][2];                        // Q as B-operand [n=q][k=d]
  #pragma unroll
  for (int rh = 0; rh < 2; ++rh)
    #pragma unroll
    for (int dh = 0; dh < 2; ++dh)
      aq[rh][dh] = *(const bf16x8*)&Q[(size_t)(q0 + rh*16 + lrow)*64 + dh*32 + quad*8];

  f32x4 acc[2][4];   // O^T: acc[rh][db]: d = db*16+quad*4+r, q = lrow
  #pragma unroll
  for (int rh = 0; rh < 2; ++rh)
    #pragma unroll
    for (int db = 0; db < 4; ++db) acc[rh][db] = zero4;
  f32x4 accl[2] = {zero4, zero4};         // l[q=lrow] (all rows equal)

  stage(0, 0);             // prologue prefetch

  for (int t = 0; t < T; ++t) {
    const int kv0 = t * 64;
    const int buf = t & 1;
    __syncthreads();       // vmcnt drain -> tile t resident; buf[t+1] readers done
    if (t + 1 < T) stage(t + 1, buf ^ 1);

    if (t < nt) {
      const bool diag = (t == nt - 1);

      auto phalf = [&](int half) {
        #pragma unroll
        for (int ch = 0; ch < 2; ++ch) {
          const int c = half*2 + ch;
          const int r0 = c*16 + lrow;
          bf16x8 k0 = *(const bf16x8*)&sK[buf][(r0*8 + (quad       ^ swz))*8];
          bf16x8 k1 = *(const bf16x8*)&sK[buf][(r0*8 + ((quad + 4) ^ swz))*8];
          #pragma unroll
          for (int rh = 0; rh < 2; ++rh) {
            f32x4 st = MFMA16(k0, aq[rh][0], zero4);   // S^T subtile
            st = MFMA16(k1, aq[rh][1], st);
            if (diag) {   // causal: kv = kv0+c*16+quad*4+r, q = q0+rh*16+lrow
              #pragma unroll
              for (int r = 0; r < 4; ++r)
                if (kv0 + c*16 + quad*4 + r > q0 + rh*16 + lrow)
                  st[r] = -1e30f;
            }
            uint2 w;
            w.x = pack_bf16x2_rtz(EXP2(st[0] - 16.0f), EXP2(st[1] - 16.0f));
            w.y = pack_bf16x2_rtz(EXP2(st[2] - 16.0f), EXP2(st[3] - 16.0f));
            // write granule g16 = 2*ch + (quad>>1), XOR-swizzled by sw2
            *(uint2*)&sp[(rh*16 + lrow)*32 + (((2*ch + (quad >> 1)) ^ sw2) << 3)
                         + ((quad & 1) << 2)] = w;
          }
        }
        DS_HANDOFF_FENCE();   // P writes complete before pa reads issue
        bf16x8 pa0 = *(const bf16x8*)&sp[(lrow)     *32 + ((quad ^ sw2) << 3)];
        bf16x8 pa1 = *(const bf16x8*)&sp[(16 + lrow)*32 + ((quad ^ sw2) << 3)];
        #pragma unroll
        for (int db = 0; db < 4; ++db) {
          const int rv = db*16 + lrow;
          bf16x8 v = *(const bf16x8*)&sV[buf][(rv*8 + ((half*4 + quad) ^ swz))*8];
          acc[0][db] = MFMA16(v, pa0, acc[0][db]);     // O^T
          acc[1][db] = MFMA16(v, pa1, acc[1][db]);
        }
        accl[0] = MFMA16(ones, pa0, accl[0]);
        accl[1] = MFMA16(ones, pa1, accl[1]);
        DS_HANDOFF_FENCE();   // pa reads complete before next half's P writes
      };

      phalf(0);
      // diag tiles for waves 0/2 (q0 == kv0): kv half 1 entirely above the
      // causal boundary -> skip (P would be all zeros).
      if (!(diag && !(wave & 1))) phalf(1);
    }
  }

  // epilogue: O^T -> attn, 4 d-consecutive values per packed store
  #pragma unroll
  for (int rh = 0; rh < 2; ++rh) {
    float inv = 1.0f / accl[rh][0];
    size_t rowbase = ((size_t)(b*SEQ + q0 + rh*16 + lrow))*D_MODEL + h*64;
    #pragma unroll
    for (int db = 0; db < 4; ++db) {
      ushort4 o;
      o.x = f2b(acc[rh][db][0] * inv);
      o.y = f2b(acc[rh][db][1] * inv);
      o.z = f2b(acc[rh][db][2] * inv);
      o.w = f2b(acc[rh][db][3] * inv);
      *(ushort4*)&attn[rowbase + db*16 + quad*4] = o;
    }
  }
}

extern "C" void kernel_launch(void* const* d_in, const int* in_sizes, int n_in,
                              void* d_out, int out_size, void* d_ws, size_t ws_size,
                              hipStream_t stream) {
  const float* x  = (const float*)d_in[0];
  const int*  pos = (const int*)d_in[1];
  const float* Wq = (const float*)d_in[2];
  const float* Wk = (const float*)d_in[3];
  const float* Wv = (const float*)d_in[4];
  const float* Wo = (const float*)d_in[5];
  float* out = (float*)d_out;

  char* ws = (char*)d_ws;
  // workspace layout (bytes); total 75,497,472
  unsigned short* xb   = (unsigned short*)(ws);              // 16 MB, reused as attn buffer
  unsigned short* wqkv = (unsigned short*)(ws + 16777216);   // 6 MB  [3072][1024]
  unsigned short* wo   = (unsigned short*)(ws + 23068672);   // 2 MB  [1024][1024]
  unsigned short* qb   = (unsigned short*)(ws + 25165824);   // 16 MB [bh][s][d]
  unsigned short* kb   = (unsigned short*)(ws + 41943040);   // 16 MB [bh][s][d]
  unsigned short* vtb  = (unsigned short*)(ws + 58720256);   // 16 MB [bh][d][s]
  unsigned short* attn = xb;                                 // reuse

  // 1) all casts in ONE launch (x + 4 weights)
  cast_all_kernel<<<12288, 256, 0, stream>>>(
      x, Wq, Wk, Wv, Wo, xb, wqkv, wqkv + 1048576, wqkv + 2097152, wo);

  // 2) QKV projection (+fused RoPE on q,k): [8192,3072] = xb * wqkv^T
  gemm_bt<1,128><<<dim3(BS/128, 3072/128), 256, 0, stream>>>(
      xb, wqkv, nullptr, qb, kb, vtb, pos, BS, 3*D_MODEL, D_MODEL);

  // 3) causal flash attention -> attn [b,s,1024] bf16
  flash_kernel<<<dim3(BHN, 16), 256, 0, stream>>>(qb, kb, vtb, attn);

  // 4) output projection: out = attn * wo^T (fp32 out), 128x128 tiles
  gemm_bt<0,128><<<dim3(BS/128, D_MODEL/128), 256, 0, stream>>>(
      attn, wo, out, nullptr, nullptr, nullptr, nullptr, BS, D_MODEL, D_MODEL);

  (void)in_sizes; (void)n_in; (void)out_size; (void)ws_size;
}

// Round 13
// 227.547 us; speedup vs baseline: 1.8946x; 1.0380x over previous
//
#include <hip/hip_runtime.h>
#include <math.h>
#include <stddef.h>

#define D_MODEL 1024
#define NUM_HEADS 16
#define D_K 64
#define BATCH 4
#define SEQ 2048
#define BS (BATCH*SEQ)        /* 8192 */
#define BHN (BATCH*NUM_HEADS) /* 64  */

typedef short bf16x8 __attribute__((ext_vector_type(8)));
typedef float f32x4  __attribute__((ext_vector_type(4)));

#define MFMA16(a,b,c) __builtin_amdgcn_mfma_f32_16x16x32_bf16(a,b,c,0,0,0)

typedef __attribute__((address_space(1))) const unsigned int guint;
typedef __attribute__((address_space(3))) unsigned int luint;

extern "C" __device__ float __ocml_native_exp2_f32(float);   // v_exp_f32
#define EXP2(x) __ocml_native_exp2_f32(x)

// Hardened same-wave LDS write->read handoff (PROVEN round 10): compiler
// memory fence + HW drain of this wave's DS queue + scheduler pin.
// Round-9 evidence: same binary diverged across graph replays with only
// wave_barrier -> the DS pipe hazard is real at HW level; lgkmcnt(0) fixes.
#define DS_HANDOFF_FENCE() do {                                  \
    asm volatile("s_waitcnt lgkmcnt(0)" ::: "memory");           \
    __builtin_amdgcn_sched_barrier(0);                           \
  } while (0)

static __device__ __forceinline__ unsigned short f2b(float f) {
  union { float f; unsigned int u; } cv; cv.f = f;
  unsigned int u = cv.u;
  u += 0x7fffu + ((u >> 16) & 1u);   // RTNE (inputs are finite)
  return (unsigned short)(u >> 16);
}
static __device__ __forceinline__ float b2f(unsigned short h) {
  union { unsigned int u; float f; } cv; cv.u = ((unsigned int)h) << 16;
  return cv.f;
}
// pack two floats as truncated bf16 pair in ONE v_perm: [bf16(lo) | bf16(hi)<<16]
static __device__ __forceinline__ unsigned pack_bf16x2_rtz(float lo, float hi) {
  return __builtin_amdgcn_perm(__builtin_bit_cast(unsigned, lo),
                               __builtin_bit_cast(unsigned, hi),
                               0x03020706u);
}

// ---------------- fp32 -> bf16 cast, ALL tensors in one launch ----------------
__global__ void cast_all_kernel(const float* __restrict__ x,
                                const float* __restrict__ w0, const float* __restrict__ w1,
                                const float* __restrict__ w2, const float* __restrict__ w3,
                                unsigned short* __restrict__ xb,
                                unsigned short* __restrict__ d0, unsigned short* __restrict__ d1,
                                unsigned short* __restrict__ d2, unsigned short* __restrict__ d3) {
  int i = blockIdx.x * 256 + threadIdx.x;   // 0 .. 3,145,727
  const float* s; unsigned short* d; int k;
  if (i < 2097152) {
    s = x; d = xb; k = i;
  } else {
    int r = i - 2097152;
    int w = r >> 18;            // 0..3 (262144 = 2^18 float4 per weight)
    k = r & 262143;
    switch (w) {
      case 0:  s = w0; d = d0; break;
      case 1:  s = w1; d = d1; break;
      case 2:  s = w2; d = d2; break;
      default: s = w3; d = d3; break;
    }
  }
  float4 v = ((const float4*)s)[k];
  ushort4 o;
  o.x = f2b(v.x); o.y = f2b(v.y); o.z = f2b(v.z); o.w = f2b(v.w);
  ((ushort4*)d)[k] = o;
}

// ---------------- bf16 GEMM: C[M,N] = A[M,K] * Bw[N,K]^T ----------------
// EPI==1: fused RoPE on q/k via NATIVE v_sin/v_cos (revolutions domain, fract
// reduction) — no sincosf (round-6: OCML sincos scratch -> 1.58 GB writes).
template<int EPI, int TN>
__global__ __launch_bounds__(256, 3) void gemm_bt(
    const unsigned short* __restrict__ A,
    const unsigned short* __restrict__ Bw,
    float* __restrict__ Cf,
    unsigned short* __restrict__ qb,
    unsigned short* __restrict__ kb,
    unsigned short* __restrict__ vtb,
    const int* __restrict__ pos,
    int M, int N, int K)
{
  constexpr int NJ = TN / 32;            // B-frag cols per wave (4 or 2)
  __shared__ __align__(16) unsigned short sA[128*64];
  __shared__ __align__(16) unsigned short sB[TN*64];
  const int tid  = threadIdx.x;
  const int wave = tid >> 6, lane = tid & 63;
  const int lrow = lane & 15, quad = lane >> 4;
  const int wm = (wave & 1) * 64, wn = (wave >> 1) * (TN/2);
  const int m0 = blockIdx.x * 128, n0 = blockIdx.y * TN;
  const int swz = lrow & 7;

  const f32x4 zero4 = {0.f, 0.f, 0.f, 0.f};
  f32x4 acc[4][NJ];
  for (int i = 0; i < 4; ++i)
    for (int j = 0; j < NJ; ++j) acc[i][j] = zero4;

  for (int kt = 0; kt < K; kt += 64) {
    __syncthreads();
    #pragma unroll
    for (int it = 0; it < 4; ++it) {
      int t = it*256 + tid;                 // A slot 0..1023 (16B chunks)
      int row = t >> 3;
      int c8  = (t & 7) ^ (row & 7);        // XOR-swizzled source chunk
      __builtin_amdgcn_global_load_lds(
          (guint*)&A[(size_t)(m0 + row)*K + kt + c8*8], (luint*)&sA[t*8], 16, 0, 0);
    }
    #pragma unroll
    for (int it = 0; it < TN/32; ++it) {
      int t = it*256 + tid;                 // B slot 0..TN*8-1
      int row = t >> 3;
      int c8  = (t & 7) ^ (row & 7);
      __builtin_amdgcn_global_load_lds(
          (guint*)&Bw[(size_t)(n0 + row)*K + kt + c8*8], (luint*)&sB[t*8], 16, 0, 0);
    }
    __syncthreads();
    #pragma unroll
    for (int kh = 0; kh < 2; ++kh) {
      bf16x8 af[4], bfr[NJ];
      #pragma unroll
      for (int i = 0; i < 4; ++i) {
        int ra = wm + i*16 + lrow;
        af[i] = *(const bf16x8*)&sA[ra*64 + (((kh*4 + quad) ^ swz))*8];
      }
      #pragma unroll
      for (int j = 0; j < NJ; ++j) {
        int rb = wn + j*16 + lrow;
        bfr[j] = *(const bf16x8*)&sB[rb*64 + (((kh*4 + quad) ^ swz))*8];
      }
      #pragma unroll
      for (int i = 0; i < 4; ++i)
        #pragma unroll
        for (int j = 0; j < NJ; ++j)
          acc[i][j] = MFMA16(af[i], bfr[j], acc[i][j]);
    }
  }

  if (EPI == 0) {
    for (int i = 0; i < 4; ++i)
      for (int j = 0; j < NJ; ++j)
        for (int r = 0; r < 4; ++r) {
          int m = m0 + wm + i*16 + quad*4 + r;
          int n = n0 + wn + j*16 + lrow;
          Cf[(size_t)m*N + n] = acc[i][j][r];
        }
  } else if (n0 >= 2048) {
    // V blocks: 4 r-values are s-consecutive in vt -> one packed store each
    for (int i = 0; i < 4; ++i) {
      int mb = m0 + wm + i*16 + quad*4;
      int bb = mb >> 11, s = mb & 2047;
      for (int j = 0; j < NJ; ++j) {
        int rr = (n0 + wn + j*16 + lrow) & 1023;
        size_t base = ((size_t)(bb*16 + (rr >> 6))*64 + (rr & 63))*2048 + s;
        ushort4 o;
        o.x = f2b(acc[i][j][0]); o.y = f2b(acc[i][j][1]);
        o.z = f2b(acc[i][j][2]); o.w = f2b(acc[i][j][3]);
        *(ushort4*)&vtb[base] = o;
      }
    }
  } else {
    // q/k blocks with fused RoPE (native trig, scratch-free).
    const float QS = 0.18033688011112042f;     // (1/8) * log2(e)
    const float INV2PI = 0.15915493667125702f; // 1/(2*pi)
    const bool evenl = ((lane & 1) == 0);
    const int bb = m0 >> 11;                   // batch (block-uniform)
    float rf[NJ];                              // per-lane rope factor, rev units
    #pragma unroll
    for (int j = 0; j < NJ; ++j) {
      const int jp = ((n0 + wn + j*16 + lrow) & 63) >> 1;   // pair idx 0..31
      rf[j] = exp2f(-0.4152410118609203f * (float)jp) * INV2PI;
    }
    for (int i = 0; i < 4; ++i) {
      const int mbase = m0 + wm + i*16 + quad*4;
      float ps[4];
      #pragma unroll
      for (int r = 0; r < 4; ++r) ps[r] = (float)pos[(mbase + r) & 2047];
      for (int j = 0; j < NJ; ++j) {
        const int n = n0 + wn + j*16 + lrow;
        const int which = n >> 10;             // 0 = q, 1 = k (block-uniform)
        const int rr = n & 1023, h = rr >> 6, d = rr & 63;
        const size_t bh = (size_t)(bb*16 + h);
        #pragma unroll
        for (int r = 0; r < 4; ++r) {
          const int s = (mbase + r) & 2047;
          float v = acc[i][j][r];
          float p = __shfl_xor(v, 1);          // partner (same row, d^1)
          float rev = ps[r] * rf[j];
          rev = rev - floorf(rev);             // [0,1) revolutions
          float sn = __builtin_amdgcn_sinf(rev);   // sin(2*pi*rev)
          float c  = __builtin_amdgcn_cosf(rev);
          // d even: v*c - p*sn ; d odd: v*c + p*sn
          float out = fmaf(evenl ? -p : p, sn, v * c);
          if (which == 0) out *= QS;
          unsigned short bv = f2b(out);
          if (which == 0) qb[(bh*2048 + s)*64 + d] = bv;
          else            kb[(bh*2048 + s)*64 + d] = bv;
        }
      }
    }
  }
}

// ---- causal flash attention (S^T/O^T form), double-buffered K/V staging.
// [Round-10 verified version. The 64-q/wave restructure is PERMANENTLY
//  SHELVED: NaN'd 4x (rounds 2,3,4,11) under four distinct sub-hypotheses
//  including the proven DS fence; falsifier budget exhausted.]
// T5 s_setprio(1) around the PV MFMA cluster (catalog m191: +4-7% attn;
// blocks independent + 4/CU -> scheduler has waves at different phases to
// arbitrate). Pure hint; zero correctness risk.
__global__ __launch_bounds__(256, 4) void flash_kernel(
    const unsigned short* __restrict__ q,    // [bh][s][d]  (pre-scaled by log2e/8)
    const unsigned short* __restrict__ kk,   // [bh][s][d]
    const unsigned short* __restrict__ vt,   // [bh][d][s]
    unsigned short* __restrict__ attn)       // [b][s][h*64+d]
{
  __shared__ __align__(16) unsigned short sK[2][64*64];   // XOR-swizzled chunks
  __shared__ __align__(16) unsigned short sV[2][64*64];
  __shared__ __align__(16) unsigned short sP[4][32*32];   // per-wave P^T halves
  const int tid  = threadIdx.x;
  const int wave = tid >> 6, lane = tid & 63;
  const int lrow = lane & 15, quad = lane >> 4;
  const int bh = blockIdx.x;                // XCD = bid%8 = bh%8
  const int b = bh >> 4, h = bh & 15;
  const int y = blockIdx.y;                 // 0..15
  const int J = (y < 4) ? (15 - y) : (y < 8) ? (y + 4) : (y < 12) ? (15 - y) : (y - 12);

  const unsigned short* Q  = q  + (size_t)bh * SEQ * D_K;
  const unsigned short* Kp = kk + (size_t)bh * SEQ * D_K;
  const unsigned short* Vt = vt + (size_t)bh * SEQ * D_K;
  unsigned short* sp = sP[wave];

  bf16x8 ones;
  #pragma unroll
  for (int z = 0; z < 8; ++z) ones[z] = (short)0x3F80;   // bf16 1.0
  const f32x4 zero4 = {0.f, 0.f, 0.f, 0.f};
  const int swz = lrow & 7;          // K/V chunk swizzle key
  const int sw2 = (lrow >> 1) & 3;   // sP 16B-granule swizzle key

  auto stage = [&](int t, int buf) {
    const int kv0 = t * 64;
    #pragma unroll
    for (int rr = 0; rr < 2; ++rr) {
      int s = rr*256 + tid;               // LDS slot 0..511 (16B chunks)
      int row = s >> 3;
      int c8  = (s & 7) ^ (row & 7);      // XOR-swizzled source chunk
      __builtin_amdgcn_global_load_lds(
          (guint*)&Kp[(size_t)(kv0 + row)*64 + c8*8], (luint*)&sK[buf][s*8], 16, 0, 0);
      __builtin_amdgcn_global_load_lds(
          (guint*)&Vt[(size_t)row*2048 + kv0 + c8*8], (luint*)&sV[buf][s*8], 16, 0, 0);
    }
  };

  const int T = 2*(J + 1);                // kv tiles needed by the block
  const int nt = 2*J + (wave >> 1) + 1;   // tiles needed by THIS wave
  const int q0 = J*128 + wave*32;         // this wave's first q row

  bf16x8 aq[2][2];                        // Q as B-operand [n=q][k=d]
  #pragma unroll
  for (int rh = 0; rh < 2; ++rh)
    #pragma unroll
    for (int dh = 0; dh < 2; ++dh)
      aq[rh][dh] = *(const bf16x8*)&Q[(size_t)(q0 + rh*16 + lrow)*64 + dh*32 + quad*8];

  f32x4 acc[2][4];   // O^T: acc[rh][db]: d = db*16+quad*4+r, q = lrow
  #pragma unroll
  for (int rh = 0; rh < 2; ++rh)
    #pragma unroll
    for (int db = 0; db < 4; ++db) acc[rh][db] = zero4;
  f32x4 accl[2] = {zero4, zero4};         // l[q=lrow] (all rows equal)

  stage(0, 0);             // prologue prefetch

  for (int t = 0; t < T; ++t) {
    const int kv0 = t * 64;
    const int buf = t & 1;
    __syncthreads();       // vmcnt drain -> tile t resident; buf[t+1] readers done
    if (t + 1 < T) stage(t + 1, buf ^ 1);

    if (t < nt) {
      const bool diag = (t == nt - 1);

      auto phalf = [&](int half) {
        #pragma unroll
        for (int ch = 0; ch < 2; ++ch) {
          const int c = half*2 + ch;
          const int r0 = c*16 + lrow;
          bf16x8 k0 = *(const bf16x8*)&sK[buf][(r0*8 + (quad       ^ swz))*8];
          bf16x8 k1 = *(const bf16x8*)&sK[buf][(r0*8 + ((quad + 4) ^ swz))*8];
          #pragma unroll
          for (int rh = 0; rh < 2; ++rh) {
            f32x4 st = MFMA16(k0, aq[rh][0], zero4);   // S^T subtile
            st = MFMA16(k1, aq[rh][1], st);
            if (diag) {   // causal: kv = kv0+c*16+quad*4+r, q = q0+rh*16+lrow
              #pragma unroll
              for (int r = 0; r < 4; ++r)
                if (kv0 + c*16 + quad*4 + r > q0 + rh*16 + lrow)
                  st[r] = -1e30f;
            }
            uint2 w;
            w.x = pack_bf16x2_rtz(EXP2(st[0] - 16.0f), EXP2(st[1] - 16.0f));
            w.y = pack_bf16x2_rtz(EXP2(st[2] - 16.0f), EXP2(st[3] - 16.0f));
            // write granule g16 = 2*ch + (quad>>1), XOR-swizzled by sw2
            *(uint2*)&sp[(rh*16 + lrow)*32 + (((2*ch + (quad >> 1)) ^ sw2) << 3)
                         + ((quad & 1) << 2)] = w;
          }
        }
        DS_HANDOFF_FENCE();   // P writes complete before pa reads issue
        bf16x8 pa0 = *(const bf16x8*)&sp[(lrow)     *32 + ((quad ^ sw2) << 3)];
        bf16x8 pa1 = *(const bf16x8*)&sp[(16 + lrow)*32 + ((quad ^ sw2) << 3)];
        __builtin_amdgcn_s_setprio(1);       // T5: favor PV MFMA cluster
        #pragma unroll
        for (int db = 0; db < 4; ++db) {
          const int rv = db*16 + lrow;
          bf16x8 v = *(const bf16x8*)&sV[buf][(rv*8 + ((half*4 + quad) ^ swz))*8];
          acc[0][db] = MFMA16(v, pa0, acc[0][db]);     // O^T
          acc[1][db] = MFMA16(v, pa1, acc[1][db]);
        }
        accl[0] = MFMA16(ones, pa0, accl[0]);
        accl[1] = MFMA16(ones, pa1, accl[1]);
        __builtin_amdgcn_s_setprio(0);
        DS_HANDOFF_FENCE();   // pa reads complete before next half's P writes
      };

      phalf(0);
      // diag tiles for waves 0/2 (q0 == kv0): kv half 1 entirely above the
      // causal boundary -> skip (P would be all zeros).
      if (!(diag && !(wave & 1))) phalf(1);
    }
  }

  // epilogue: O^T -> attn, 4 d-consecutive values per packed store
  #pragma unroll
  for (int rh = 0; rh < 2; ++rh) {
    float inv = 1.0f / accl[rh][0];
    size_t rowbase = ((size_t)(b*SEQ + q0 + rh*16 + lrow))*D_MODEL + h*64;
    #pragma unroll
    for (int db = 0; db < 4; ++db) {
      ushort4 o;
      o.x = f2b(acc[rh][db][0] * inv);
      o.y = f2b(acc[rh][db][1] * inv);
      o.z = f2b(acc[rh][db][2] * inv);
      o.w = f2b(acc[rh][db][3] * inv);
      *(ushort4*)&attn[rowbase + db*16 + quad*4] = o;
    }
  }
}

extern "C" void kernel_launch(void* const* d_in, const int* in_sizes, int n_in,
                              void* d_out, int out_size, void* d_ws, size_t ws_size,
                              hipStream_t stream) {
  const float* x  = (const float*)d_in[0];
  const int*  pos = (const int*)d_in[1];
  const float* Wq = (const float*)d_in[2];
  const float* Wk = (const float*)d_in[3];
  const float* Wv = (const float*)d_in[4];
  const float* Wo = (const float*)d_in[5];
  float* out = (float*)d_out;

  char* ws = (char*)d_ws;
  // workspace layout (bytes); total 75,497,472
  unsigned short* xb   = (unsigned short*)(ws);              // 16 MB, reused as attn buffer
  unsigned short* wqkv = (unsigned short*)(ws + 16777216);   // 6 MB  [3072][1024]
  unsigned short* wo   = (unsigned short*)(ws + 23068672);   // 2 MB  [1024][1024]
  unsigned short* qb   = (unsigned short*)(ws + 25165824);   // 16 MB [bh][s][d]
  unsigned short* kb   = (unsigned short*)(ws + 41943040);   // 16 MB [bh][s][d]
  unsigned short* vtb  = (unsigned short*)(ws + 58720256);   // 16 MB [bh][d][s]
  unsigned short* attn = xb;                                 // reuse

  // 1) all casts in ONE launch (x + 4 weights)
  cast_all_kernel<<<12288, 256, 0, stream>>>(
      x, Wq, Wk, Wv, Wo, xb, wqkv, wqkv + 1048576, wqkv + 2097152, wo);

  // 2) QKV projection (+fused RoPE on q,k): [8192,3072] = xb * wqkv^T
  gemm_bt<1,128><<<dim3(BS/128, 3072/128), 256, 0, stream>>>(
      xb, wqkv, nullptr, qb, kb, vtb, pos, BS, 3*D_MODEL, D_MODEL);

  // 3) causal flash attention -> attn [b,s,1024] bf16
  flash_kernel<<<dim3(BHN, 16), 256, 0, stream>>>(qb, kb, vtb, attn);

  // 4) output projection: out = attn * wo^T (fp32 out), 128x128 tiles
  gemm_bt<0,128><<<dim3(BS/128, D_MODEL/128), 256, 0, stream>>>(
      attn, wo, out, nullptr, nullptr, nullptr, nullptr, BS, D_MODEL, D_MODEL);

  (void)in_sizes; (void)n_in; (void)out_size; (void)ws_size;
}